// Round 1
// baseline (1157.075 us; speedup 1.0000x reference)
//
#include <hip/hip_runtime.h>

// ---------------- workspace layout (indices into uint32/float32 view) -------
// wsu[0] = min key, wsu[1] = max key (monotonic uint mapping of float)
// wsu[2..257]   = hist[256]
// wsf[258..514] = edges[257]
// wsf[515] = vmin, wsf[516] = delta, wsf[517] = inv_delta, wsf[518] = thresh
// byte offset 4096: gray[npix] (optional, if ws_size permits)
static constexpr int HIST_OFF   = 2;
static constexpr int EDGES_OFF  = 258;
static constexpr int VMIN_OFF   = 515;
static constexpr int DELTA_OFF  = 516;
static constexpr int INVD_OFF   = 517;
static constexpr int THRESH_OFF = 518;
static constexpr size_t GRAY_BYTE_OFF = 4096;

// monotonic float<->uint key (works for all non-NaN floats)
__device__ __forceinline__ unsigned fkey(float x) {
    unsigned u = __float_as_uint(x);
    return (u & 0x80000000u) ? ~u : (u | 0x80000000u);
}
__device__ __forceinline__ float keyf(unsigned k) {
    return (k & 0x80000000u) ? __uint_as_float(k & 0x7FFFFFFFu)
                             : __uint_as_float(~k);
}

// gray = ((r*wr + g*wg) + b*wb), strict f32 rounding, NO fma contraction
__device__ __forceinline__ float gray1(float r, float g, float b) {
    float t0 = __fmul_rn(r, 0.2989f);
    float t1 = __fmul_rn(g, 0.5870f);
    float t2 = __fmul_rn(b, 0.1140f);
    return __fadd_rn(__fadd_rn(t0, t1), t2);
}

__global__ void init_kernel(unsigned* __restrict__ wsu) {
    int i = threadIdx.x;
    if (i < 256) wsu[HIST_OFF + i] = 0u;
    if (i == 0) { wsu[0] = 0xFFFFFFFFu; wsu[1] = 0u; }
}

// one thread handles 4 pixels (12 floats = 3 x float4)
__global__ void gray_minmax_kernel(const float* __restrict__ in,
                                   float* __restrict__ gray,
                                   unsigned* __restrict__ wsu, int npix4) {
    int t = blockIdx.x * blockDim.x + threadIdx.x;
    unsigned mn = 0xFFFFFFFFu, mx = 0u;
    if (t < npix4) {
        const float4* in4 = (const float4*)in + (size_t)t * 3;
        float4 c0 = in4[0], c1 = in4[1], c2 = in4[2];
        float g0 = gray1(c0.x, c0.y, c0.z);
        float g1 = gray1(c0.w, c1.x, c1.y);
        float g2 = gray1(c1.z, c1.w, c2.x);
        float g3 = gray1(c2.y, c2.z, c2.w);
        if (gray) ((float4*)gray)[t] = make_float4(g0, g1, g2, g3);
        unsigned k0 = fkey(g0), k1 = fkey(g1), k2 = fkey(g2), k3 = fkey(g3);
        mn = min(min(k0, k1), min(k2, k3));
        mx = max(max(k0, k1), max(k2, k3));
    }
    // wave64 butterfly reduce
    for (int off = 32; off > 0; off >>= 1) {
        mn = min(mn, (unsigned)__shfl_xor((int)mn, off, 64));
        mx = max(mx, (unsigned)__shfl_xor((int)mx, off, 64));
    }
    if ((threadIdx.x & 63) == 0) {
        atomicMin(&wsu[0], mn);
        atomicMax(&wsu[1], mx);
    }
}

// replicate jnp.linspace(vmin, vmax, 257) in f32:
// delta = (vmax - vmin) / 256 (exact pow2 divide), edges[i] = vmin + i*delta,
// edges[256] = vmax (endpoint). centers[255] is never selectable so endpoint
// handling only affects binning of x==vmax (clamped to bin 255 either way).
__global__ void edges_kernel(const unsigned* __restrict__ wsu,
                             float* __restrict__ wsf) {
    float vmin = keyf(wsu[0]);
    float vmax = keyf(wsu[1]);
    float delta = __fdiv_rn(__fsub_rn(vmax, vmin), 256.0f);
    int i = threadIdx.x;
    if (i <= 256) {
        float e = (i == 256) ? vmax
                             : __fadd_rn(vmin, __fmul_rn((float)i, delta));
        wsf[EDGES_OFF + i] = e;
    }
    if (i == 0) {
        wsf[VMIN_OFF]  = vmin;
        wsf[DELTA_OFF] = delta;
        wsf[INVD_OFF]  = (delta > 0.0f) ? __fdiv_rn(1.0f, delta) : 0.0f;
    }
}

__global__ void hist_kernel(const float* __restrict__ gray,
                            const float* __restrict__ in,
                            const float* __restrict__ wsf,
                            unsigned* __restrict__ wsu, int npix4) {
    __shared__ float eds[257];
    __shared__ unsigned lh[256];
    for (int i = threadIdx.x; i < 257; i += blockDim.x)
        eds[i] = wsf[EDGES_OFF + i];
    if (threadIdx.x < 256) lh[threadIdx.x] = 0u;
    __syncthreads();
    float vmin = eds[0];
    float invd = wsf[INVD_OFF];
    int t = blockIdx.x * blockDim.x + threadIdx.x;
    if (t < npix4) {
        float g[4];
        if (gray) {
            float4 g4 = ((const float4*)gray)[t];
            g[0] = g4.x; g[1] = g4.y; g[2] = g4.z; g[3] = g4.w;
        } else {
            const float4* in4 = (const float4*)in + (size_t)t * 3;
            float4 c0 = in4[0], c1 = in4[1], c2 = in4[2];
            g[0] = gray1(c0.x, c0.y, c0.z);
            g[1] = gray1(c0.w, c1.x, c1.y);
            g[2] = gray1(c1.z, c1.w, c2.x);
            g[3] = gray1(c2.y, c2.z, c2.w);
        }
#pragma unroll
        for (int j = 0; j < 4; ++j) {
            float x = g[j];
            int b = (int)(__fmul_rn(__fsub_rn(x, vmin), invd));
            b = b < 0 ? 0 : (b > 255 ? 255 : b);
            // exact searchsorted fix-up against true f32 edges
            while (b < 255 && x >= eds[b + 1]) ++b;
            while (b > 0 && x < eds[b]) --b;
            atomicAdd(&lh[b], 1u);
        }
    }
    __syncthreads();
    if (threadIdx.x < 256 && lh[threadIdx.x] != 0u)
        atomicAdd(&wsu[HIST_OFF + threadIdx.x], lh[threadIdx.x]);
}

// sequential f32 Otsu scan on one thread (order-faithful to numpy cumsum)
__global__ void otsu_kernel(const unsigned* __restrict__ wsu,
                            float* __restrict__ wsf) {
    __shared__ float histf[256];
    __shared__ float centers[256];
    __shared__ float w2a[256];
    __shared__ float s2a[256];
    int i = threadIdx.x; // blockDim = 256
    float e0 = wsf[EDGES_OFF + i];
    float e1 = wsf[EDGES_OFF + i + 1];
    centers[i] = __fmul_rn(__fadd_rn(e0, e1), 0.5f);
    histf[i] = (float)wsu[HIST_OFF + i];
    __syncthreads();
    if (i == 0) {
        float w = 0.0f, s = 0.0f;
        for (int t = 255; t >= 0; --t) {
            w = __fadd_rn(w, histf[t]);
            s = __fadd_rn(s, __fmul_rn(histf[t], centers[t]));
            w2a[t] = w;
            s2a[t] = s;
        }
        float w1 = 0.0f, s1 = 0.0f, best = -1.0f;
        int bidx = 0;
        for (int t = 0; t < 255; ++t) {
            w1 = __fadd_rn(w1, histf[t]);
            s1 = __fadd_rn(s1, __fmul_rn(histf[t], centers[t]));
            float m1 = __fdiv_rn(s1, fmaxf(w1, 1.0f));
            float m2 = __fdiv_rn(s2a[t + 1], fmaxf(w2a[t + 1], 1.0f));
            float d  = __fsub_rn(m1, m2);
            float v  = __fmul_rn(__fmul_rn(w1, w2a[t + 1]), __fmul_rn(d, d));
            if (v > best) { best = v; bidx = t; }  // first max, like argmax
        }
        wsf[THRESH_OFF] = centers[bidx];
    }
}

__global__ void binarize_kernel(const float* __restrict__ gray,
                                const float* __restrict__ in,
                                const float* __restrict__ wsf,
                                float* __restrict__ out, int npix4) {
    int t = blockIdx.x * blockDim.x + threadIdx.x;
    if (t >= npix4) return;
    float thr = wsf[THRESH_OFF];
    float g0, g1, g2, g3;
    if (gray) {
        float4 g4 = ((const float4*)gray)[t];
        g0 = g4.x; g1 = g4.y; g2 = g4.z; g3 = g4.w;
    } else {
        const float4* in4 = (const float4*)in + (size_t)t * 3;
        float4 c0 = in4[0], c1 = in4[1], c2 = in4[2];
        g0 = gray1(c0.x, c0.y, c0.z);
        g1 = gray1(c0.w, c1.x, c1.y);
        g2 = gray1(c1.z, c1.w, c2.x);
        g3 = gray1(c2.y, c2.z, c2.w);
    }
    float b0 = (g0 > thr) ? 1.0f : 0.0f;
    float b1 = (g1 > thr) ? 1.0f : 0.0f;
    float b2 = (g2 > thr) ? 1.0f : 0.0f;
    float b3 = (g3 > thr) ? 1.0f : 0.0f;
    float4* o = (float4*)out + (size_t)t * 3;
    o[0] = make_float4(b0, b0, b0, b1);
    o[1] = make_float4(b1, b1, b2, b2);
    o[2] = make_float4(b2, b3, b3, b3);
}

extern "C" void kernel_launch(void* const* d_in, const int* in_sizes, int n_in,
                              void* d_out, int out_size, void* d_ws,
                              size_t ws_size, hipStream_t stream) {
    const float* in = (const float*)d_in[0];
    float* out = (float*)d_out;
    int npix  = out_size / 3;
    int npix4 = npix / 4;                       // H*W*B divisible by 4 here
    unsigned* wsu = (unsigned*)d_ws;
    float* wsf = (float*)d_ws;
    size_t need = GRAY_BYTE_OFF + (size_t)npix * sizeof(float);
    float* gray = (ws_size >= need)
                      ? (float*)((char*)d_ws + GRAY_BYTE_OFF)
                      : nullptr;                // fallback: recompute gray
    int blocks = (npix4 + 255) / 256;

    hipLaunchKernelGGL(init_kernel, dim3(1), dim3(256), 0, stream, wsu);
    hipLaunchKernelGGL(gray_minmax_kernel, dim3(blocks), dim3(256), 0, stream,
                       in, gray, wsu, npix4);
    hipLaunchKernelGGL(edges_kernel, dim3(1), dim3(320), 0, stream, wsu, wsf);
    hipLaunchKernelGGL(hist_kernel, dim3(blocks), dim3(256), 0, stream,
                       gray, in, wsf, wsu, npix4);
    hipLaunchKernelGGL(otsu_kernel, dim3(1), dim3(256), 0, stream, wsu, wsf);
    hipLaunchKernelGGL(binarize_kernel, dim3(blocks), dim3(256), 0, stream,
                       gray, in, wsf, out, npix4);
}

// Round 2
// 291.252 us; speedup vs baseline: 3.9728x; 3.9728x over previous
//
#include <hip/hip_runtime.h>

// ---------------- workspace layout (indices into uint32/float32 view) -------
// wsu[0] = min key, wsu[1] = max key (monotonic uint mapping of float)
// wsu[2..257]   = hist[256]
// wsf[258..514] = edges[257]
// wsf[515] = vmin, wsf[516] = delta, wsf[517] = inv_delta, wsf[518] = thresh
// byte offset 4096: gray[npix] (optional, if ws_size permits)
static constexpr int HIST_OFF   = 2;
static constexpr int EDGES_OFF  = 258;
static constexpr int VMIN_OFF   = 515;
static constexpr int DELTA_OFF  = 516;
static constexpr int INVD_OFF   = 517;
static constexpr int THRESH_OFF = 518;
static constexpr size_t GRAY_BYTE_OFF = 4096;

// monotonic float<->uint key (works for all non-NaN floats)
__device__ __forceinline__ unsigned fkey(float x) {
    unsigned u = __float_as_uint(x);
    return (u & 0x80000000u) ? ~u : (u | 0x80000000u);
}
__device__ __forceinline__ float keyf(unsigned k) {
    return (k & 0x80000000u) ? __uint_as_float(k & 0x7FFFFFFFu)
                             : __uint_as_float(~k);
}

// gray = ((r*wr + g*wg) + b*wb), strict f32 rounding, NO fma contraction
__device__ __forceinline__ float gray1(float r, float g, float b) {
    float t0 = __fmul_rn(r, 0.2989f);
    float t1 = __fmul_rn(g, 0.5870f);
    float t2 = __fmul_rn(b, 0.1140f);
    return __fadd_rn(__fadd_rn(t0, t1), t2);
}

__global__ void init_kernel(unsigned* __restrict__ wsu) {
    int i = threadIdx.x;
    if (i < 256) wsu[HIST_OFF + i] = 0u;
    if (i == 0) { wsu[0] = 0xFFFFFFFFu; wsu[1] = 0u; }
}

// grid-stride; one iteration = 4 pixels (12 floats = 3 x float4) per thread.
// Per-block LDS min/max reduction -> ONE atomic pair per block.
__global__ void __launch_bounds__(256)
gray_minmax_kernel(const float* __restrict__ in, float* __restrict__ gray,
                   unsigned* __restrict__ wsu, int npix4) {
    __shared__ unsigned smn[4], smx[4];
    unsigned mn = 0xFFFFFFFFu, mx = 0u;
    int stride = gridDim.x * blockDim.x;
    for (int t = blockIdx.x * blockDim.x + threadIdx.x; t < npix4; t += stride) {
        const float4* in4 = (const float4*)in + (size_t)t * 3;
        float4 c0 = in4[0], c1 = in4[1], c2 = in4[2];
        float g0 = gray1(c0.x, c0.y, c0.z);
        float g1 = gray1(c0.w, c1.x, c1.y);
        float g2 = gray1(c1.z, c1.w, c2.x);
        float g3 = gray1(c2.y, c2.z, c2.w);
        if (gray) ((float4*)gray)[t] = make_float4(g0, g1, g2, g3);
        unsigned k0 = fkey(g0), k1 = fkey(g1), k2 = fkey(g2), k3 = fkey(g3);
        mn = min(mn, min(min(k0, k1), min(k2, k3)));
        mx = max(mx, max(max(k0, k1), max(k2, k3)));
    }
    // wave64 butterfly reduce
    for (int off = 32; off > 0; off >>= 1) {
        mn = min(mn, (unsigned)__shfl_xor((int)mn, off, 64));
        mx = max(mx, (unsigned)__shfl_xor((int)mx, off, 64));
    }
    int wave = threadIdx.x >> 6;
    if ((threadIdx.x & 63) == 0) { smn[wave] = mn; smx[wave] = mx; }
    __syncthreads();
    if (threadIdx.x == 0) {
        mn = min(min(smn[0], smn[1]), min(smn[2], smn[3]));
        mx = max(max(smx[0], smx[1]), max(smx[2], smx[3]));
        atomicMin(&wsu[0], mn);
        atomicMax(&wsu[1], mx);
    }
}

// replicate jnp.linspace(vmin, vmax, 257) in f32:
// delta = (vmax - vmin) / 256 (exact pow2 divide), edges[i] = vmin + i*delta,
// edges[256] = vmax. centers[255] is never selectable by argmax(var12) so the
// endpoint only affects binning of x==vmax (clamped to bin 255 either way).
__global__ void edges_kernel(const unsigned* __restrict__ wsu,
                             float* __restrict__ wsf) {
    float vmin = keyf(wsu[0]);
    float vmax = keyf(wsu[1]);
    float delta = __fdiv_rn(__fsub_rn(vmax, vmin), 256.0f);
    int i = threadIdx.x;
    if (i <= 256) {
        float e = (i == 256) ? vmax
                             : __fadd_rn(vmin, __fmul_rn((float)i, delta));
        wsf[EDGES_OFF + i] = e;
    }
    if (i == 0) {
        wsf[VMIN_OFF]  = vmin;
        wsf[DELTA_OFF] = delta;
        wsf[INVD_OFF]  = (delta > 0.0f) ? __fdiv_rn(1.0f, delta) : 0.0f;
    }
}

// grid-stride over gray (or recompute from in); per-block LDS hist,
// ONE global atomicAdd per bin per block.
__global__ void __launch_bounds__(256)
hist_kernel(const float* __restrict__ gray, const float* __restrict__ in,
            const float* __restrict__ wsf, unsigned* __restrict__ wsu,
            int npix4) {
    __shared__ float eds[257];
    __shared__ unsigned lh[256];
    for (int i = threadIdx.x; i < 257; i += blockDim.x)
        eds[i] = wsf[EDGES_OFF + i];
    if (threadIdx.x < 256) lh[threadIdx.x] = 0u;
    __syncthreads();
    float vmin = eds[0];
    float invd = wsf[INVD_OFF];
    int stride = gridDim.x * blockDim.x;
    for (int t = blockIdx.x * blockDim.x + threadIdx.x; t < npix4; t += stride) {
        float g[4];
        if (gray) {
            float4 g4 = ((const float4*)gray)[t];
            g[0] = g4.x; g[1] = g4.y; g[2] = g4.z; g[3] = g4.w;
        } else {
            const float4* in4 = (const float4*)in + (size_t)t * 3;
            float4 c0 = in4[0], c1 = in4[1], c2 = in4[2];
            g[0] = gray1(c0.x, c0.y, c0.z);
            g[1] = gray1(c0.w, c1.x, c1.y);
            g[2] = gray1(c1.z, c1.w, c2.x);
            g[3] = gray1(c2.y, c2.z, c2.w);
        }
#pragma unroll
        for (int j = 0; j < 4; ++j) {
            float x = g[j];
            int b = (int)(__fmul_rn(__fsub_rn(x, vmin), invd));
            b = b < 0 ? 0 : (b > 255 ? 255 : b);
            // exact searchsorted fix-up against true f32 edges
            while (b < 255 && x >= eds[b + 1]) ++b;
            while (b > 0 && x < eds[b]) --b;
            atomicAdd(&lh[b], 1u);
        }
    }
    __syncthreads();
    if (threadIdx.x < 256 && lh[threadIdx.x] != 0u)
        atomicAdd(&wsu[HIST_OFF + threadIdx.x], lh[threadIdx.x]);
}

// sequential f32 Otsu scan on one thread (order-faithful to numpy cumsum)
__global__ void otsu_kernel(const unsigned* __restrict__ wsu,
                            float* __restrict__ wsf) {
    __shared__ float histf[256];
    __shared__ float centers[256];
    __shared__ float w2a[256];
    __shared__ float s2a[256];
    int i = threadIdx.x; // blockDim = 256
    float e0 = wsf[EDGES_OFF + i];
    float e1 = wsf[EDGES_OFF + i + 1];
    centers[i] = __fmul_rn(__fadd_rn(e0, e1), 0.5f);
    histf[i] = (float)wsu[HIST_OFF + i];
    __syncthreads();
    if (i == 0) {
        float w = 0.0f, s = 0.0f;
        for (int t = 255; t >= 0; --t) {
            w = __fadd_rn(w, histf[t]);
            s = __fadd_rn(s, __fmul_rn(histf[t], centers[t]));
            w2a[t] = w;
            s2a[t] = s;
        }
        float w1 = 0.0f, s1 = 0.0f, best = -1.0f;
        int bidx = 0;
        for (int t = 0; t < 255; ++t) {
            w1 = __fadd_rn(w1, histf[t]);
            s1 = __fadd_rn(s1, __fmul_rn(histf[t], centers[t]));
            float m1 = __fdiv_rn(s1, fmaxf(w1, 1.0f));
            float m2 = __fdiv_rn(s2a[t + 1], fmaxf(w2a[t + 1], 1.0f));
            float d  = __fsub_rn(m1, m2);
            float v  = __fmul_rn(__fmul_rn(w1, w2a[t + 1]), __fmul_rn(d, d));
            if (v > best) { best = v; bidx = t; }  // first max, like argmax
        }
        wsf[THRESH_OFF] = centers[bidx];
    }
}

__global__ void __launch_bounds__(256)
binarize_kernel(const float* __restrict__ gray, const float* __restrict__ in,
                const float* __restrict__ wsf, float* __restrict__ out,
                int npix4) {
    int t = blockIdx.x * blockDim.x + threadIdx.x;
    if (t >= npix4) return;
    float thr = wsf[THRESH_OFF];
    float g0, g1, g2, g3;
    if (gray) {
        float4 g4 = ((const float4*)gray)[t];
        g0 = g4.x; g1 = g4.y; g2 = g4.z; g3 = g4.w;
    } else {
        const float4* in4 = (const float4*)in + (size_t)t * 3;
        float4 c0 = in4[0], c1 = in4[1], c2 = in4[2];
        g0 = gray1(c0.x, c0.y, c0.z);
        g1 = gray1(c0.w, c1.x, c1.y);
        g2 = gray1(c1.z, c1.w, c2.x);
        g3 = gray1(c2.y, c2.z, c2.w);
    }
    float b0 = (g0 > thr) ? 1.0f : 0.0f;
    float b1 = (g1 > thr) ? 1.0f : 0.0f;
    float b2 = (g2 > thr) ? 1.0f : 0.0f;
    float b3 = (g3 > thr) ? 1.0f : 0.0f;
    float4* o = (float4*)out + (size_t)t * 3;
    o[0] = make_float4(b0, b0, b0, b1);
    o[1] = make_float4(b1, b1, b2, b2);
    o[2] = make_float4(b2, b3, b3, b3);
}

extern "C" void kernel_launch(void* const* d_in, const int* in_sizes, int n_in,
                              void* d_out, int out_size, void* d_ws,
                              size_t ws_size, hipStream_t stream) {
    const float* in = (const float*)d_in[0];
    float* out = (float*)d_out;
    int npix  = out_size / 3;
    int npix4 = npix / 4;                       // H*W*B divisible by 4 here
    unsigned* wsu = (unsigned*)d_ws;
    float* wsf = (float*)d_ws;
    size_t need = GRAY_BYTE_OFF + (size_t)npix * sizeof(float);
    float* gray = (ws_size >= need)
                      ? (float*)((char*)d_ws + GRAY_BYTE_OFF)
                      : nullptr;                // fallback: recompute gray

    hipLaunchKernelGGL(init_kernel, dim3(1), dim3(256), 0, stream, wsu);
    // 2048 blocks: 8/CU, grid-stride; only 2048 global atomic pairs total
    hipLaunchKernelGGL(gray_minmax_kernel, dim3(2048), dim3(256), 0, stream,
                       in, gray, wsu, npix4);
    hipLaunchKernelGGL(edges_kernel, dim3(1), dim3(320), 0, stream, wsu, wsf);
    // 1024 blocks: 1024 global atomics per bin total (vs 32768 before)
    hipLaunchKernelGGL(hist_kernel, dim3(1024), dim3(256), 0, stream,
                       gray, in, wsf, wsu, npix4);
    hipLaunchKernelGGL(otsu_kernel, dim3(1), dim3(256), 0, stream, wsu, wsf);
    int blocks = (npix4 + 255) / 256;
    hipLaunchKernelGGL(binarize_kernel, dim3(blocks), dim3(256), 0, stream,
                       gray, in, wsf, out, npix4);
}